// Round 9
// baseline (514.934 us; speedup 1.0000x reference)
//
#include <hip/hip_runtime.h>
#include <hip/hip_bf16.h>

#define HW1K  1048576    // 1024*1024

typedef float f4 __attribute__((ext_vector_type(4)));
typedef float f2 __attribute__((ext_vector_type(2)));

__device__ __forceinline__ f4 relu4(f4 v) {
    v.x = fmaxf(v.x, 0.0f); v.y = fmaxf(v.y, 0.0f);
    v.z = fmaxf(v.z, 0.0f); v.w = fmaxf(v.w, 0.0f);
    return v;
}

// Weight-prep: OIHW -> wp[layer_base + (ci*9+ky*3+kx)*COUT + co] (co fastest:
// coalesced, f4-aligned over co; all layer bases mult of 4).
// Bases: L1@0(432) L2@432(4608) L3@5040(9216) L4@14256(18432) L5@32688(36864)
// L6@69552(55296), total 124848.
__global__ void prep_w(const float* __restrict__ w1, const float* __restrict__ w2,
                       const float* __restrict__ w3, const float* __restrict__ w4,
                       const float* __restrict__ w5, const float* __restrict__ w6,
                       float* __restrict__ wp) {
    int i = blockIdx.x * 256 + threadIdx.x;
    if (i >= 124848) return;
    const float* src; int base, cin, cout;
    if      (i < 432)   { src = w1; base = 0;     cin = 3;  cout = 16; }
    else if (i < 5040)  { src = w2; base = 432;   cin = 16; cout = 32; }
    else if (i < 14256) { src = w3; base = 5040;  cin = 32; cout = 32; }
    else if (i < 32688) { src = w4; base = 14256; cin = 32; cout = 64; }
    else if (i < 69552) { src = w5; base = 32688; cin = 64; cout = 64; }
    else                { src = w6; base = 69552; cin = 64; cout = 96; }
    int r  = i - base;
    int kk = r / cout;
    int co = r % cout;
    int ci = kk / 9;
    int t9 = kk % 9;
    wp[i] = src[(co * cin + ci) * 9 + t9];
}

// ---------------------------------------------------------------------------
// Strip conv layer, 512 threads, NCO=4 (f4 weights). Thread = (cog, strip
// slot). Strip loop NOT unrolled (#pragma unroll 1) so only one strip's
// a[3][4] window (48 VGPR) is live at a time -> total pressure < 128.
// Clamped duplicate slots redo the last strip (same value, benign).
// Strides SI=CIN+4, SO=COUT+4 (16B-aligned).
template <int WIN, int CIN, int COUT, int SPT>
__device__ __forceinline__ void layer_s4(const float* __restrict__ sIn, float* __restrict__ sOut,
                                         const float* __restrict__ wp, const float* __restrict__ bias) {
    constexpr int WOUT  = WIN - 2;
    constexpr int SI    = CIN + 4;
    constexpr int SO    = COUT + 4;
    constexpr int COG   = COUT / 4;
    constexpr int SLOTS = 512 / COG;
    constexpr int HSTR  = WOUT / 2;
    constexpr int NSTR  = WOUT * HSTR;

    const int t   = threadIdx.x;
    const int cog = t % COG;
    const int co0 = cog * 4;
    const int ps  = t / COG;
    const f4 bs   = *(const f4*)(bias + co0);

    #pragma unroll 1
    for (int s = 0; s < SPT; ++s) {
        int ss = ps + s * SLOTS;
        if (ss > NSTR - 1) ss = NSTR - 1;
        const int row  = ss / HSTR;
        const int col2 = (ss % HSTR) * 2;
        const int base = (row * WIN + col2) * SI;

        f4 acc0 = bs, acc1 = bs;

        for (int ci4 = 0; ci4 < CIN / 4; ++ci4) {
            f4 a[3][4];
            #pragma unroll
            for (int r = 0; r < 3; ++r)
                #pragma unroll
                for (int c = 0; c < 4; ++c)
                    a[r][c] = *(const f4*)(sIn + base + (r * WIN + c) * SI + ci4 * 4);
            #pragma unroll
            for (int cc = 0; cc < 4; ++cc)
                #pragma unroll
                for (int ky = 0; ky < 3; ++ky)
                    #pragma unroll
                    for (int kx = 0; kx < 3; ++kx) {
                        f4 w = *(const f4*)(wp + ((ci4 * 4 + cc) * 9 + ky * 3 + kx) * COUT + co0);
                        acc0 += w * a[ky][kx][cc];
                        acc1 += w * a[ky][kx + 1][cc];
                    }
        }
        const int opx = row * WOUT + col2;
        *(f4*)(sOut + opx * SO + co0)       = relu4(acc0);
        *(f4*)(sOut + (opx + 1) * SO + co0) = relu4(acc1);
    }
}

// Strip layer, NCO=2 (f2 weights/acc). Used for L4 so all 512 threads stay
// busy (COG=32, SLOTS=16, SPT=2 covers 18 strips w/ duplicates).
template <int WIN, int CIN, int COUT, int SPT>
__device__ __forceinline__ void layer_s2co(const float* __restrict__ sIn, float* __restrict__ sOut,
                                           const float* __restrict__ wp, const float* __restrict__ bias) {
    constexpr int WOUT  = WIN - 2;
    constexpr int SI    = CIN + 4;
    constexpr int SO    = COUT + 4;
    constexpr int COG   = COUT / 2;
    constexpr int SLOTS = 512 / COG;
    constexpr int HSTR  = WOUT / 2;
    constexpr int NSTR  = WOUT * HSTR;

    const int t   = threadIdx.x;
    const int cog = t % COG;
    const int co0 = cog * 2;
    const int ps  = t / COG;
    const f2 bs   = *(const f2*)(bias + co0);

    #pragma unroll 1
    for (int s = 0; s < SPT; ++s) {
        int ss = ps + s * SLOTS;
        if (ss > NSTR - 1) ss = NSTR - 1;
        const int row  = ss / HSTR;
        const int col2 = (ss % HSTR) * 2;
        const int base = (row * WIN + col2) * SI;

        f2 acc0 = bs, acc1 = bs;

        for (int ci4 = 0; ci4 < CIN / 4; ++ci4) {
            f4 a[3][4];
            #pragma unroll
            for (int r = 0; r < 3; ++r)
                #pragma unroll
                for (int c = 0; c < 4; ++c)
                    a[r][c] = *(const f4*)(sIn + base + (r * WIN + c) * SI + ci4 * 4);
            #pragma unroll
            for (int cc = 0; cc < 4; ++cc)
                #pragma unroll
                for (int ky = 0; ky < 3; ++ky)
                    #pragma unroll
                    for (int kx = 0; kx < 3; ++kx) {
                        f2 w = *(const f2*)(wp + ((ci4 * 4 + cc) * 9 + ky * 3 + kx) * COUT + co0);
                        acc0 += w * a[ky][kx][cc];
                        acc1 += w * a[ky][kx + 1][cc];
                    }
        }
        const int opx = row * WOUT + col2;
        f2 v0; v0.x = fmaxf(acc0.x, 0.f); v0.y = fmaxf(acc0.y, 0.f);
        f2 v1; v1.x = fmaxf(acc1.x, 0.f); v1.y = fmaxf(acc1.y, 0.f);
        *(f2*)(sOut + opx * SO + co0)       = v0;
        *(f2*)(sOut + (opx + 1) * SO + co0) = v1;
    }
}

// 1-px-per-thread, NCO=4 (L3: 64 px x 8 cog = 512 exact).
template <int WIN, int CIN, int COUT>
__device__ __forceinline__ void layer_p4(const float* __restrict__ sIn, float* __restrict__ sOut,
                                         const float* __restrict__ wp, const float* __restrict__ bias) {
    constexpr int WOUT = WIN - 2;
    constexpr int SI   = CIN + 4;
    constexpr int SO   = COUT + 4;
    constexpr int COG  = COUT / 4;

    const int t   = threadIdx.x;
    const int cog = t % COG;
    const int co0 = cog * 4;
    const int px  = t / COG;
    const int row = px / WOUT, col = px % WOUT;
    const int base = (row * WIN + col) * SI;

    f4 acc = *(const f4*)(bias + co0);

    for (int ci4 = 0; ci4 < CIN / 4; ++ci4) {
        f4 a[3][3];
        #pragma unroll
        for (int r = 0; r < 3; ++r)
            #pragma unroll
            for (int c = 0; c < 3; ++c)
                a[r][c] = *(const f4*)(sIn + base + (r * WIN + c) * SI + ci4 * 4);
        #pragma unroll
        for (int cc = 0; cc < 4; ++cc)
            #pragma unroll
            for (int k = 0; k < 9; ++k) {
                f4 w = *(const f4*)(wp + ((ci4 * 4 + cc) * 9 + k) * COUT + co0);
                acc += w * a[k / 3][k % 3][cc];
            }
    }
    *(f4*)(sOut + px * SO + co0) = relu4(acc);
}

// 1-px-per-thread, NCO=2 (L5: 16 px x 32 cog = 512 exact).
template <int WIN, int CIN, int COUT>
__device__ __forceinline__ void layer_p2co(const float* __restrict__ sIn, float* __restrict__ sOut,
                                           const float* __restrict__ wp, const float* __restrict__ bias) {
    constexpr int WOUT = WIN - 2;
    constexpr int SI   = CIN + 4;
    constexpr int SO   = COUT + 4;
    constexpr int COG  = COUT / 2;

    const int t   = threadIdx.x;
    const int cog = t % COG;
    const int co0 = cog * 2;
    const int px  = t / COG;
    const int row = px / WOUT, col = px % WOUT;
    const int base = (row * WIN + col) * SI;

    f2 acc = *(const f2*)(bias + co0);

    for (int ci4 = 0; ci4 < CIN / 4; ++ci4) {
        f4 a[3][3];
        #pragma unroll
        for (int r = 0; r < 3; ++r)
            #pragma unroll
            for (int c = 0; c < 3; ++c)
                a[r][c] = *(const f4*)(sIn + base + (r * WIN + c) * SI + ci4 * 4);
        #pragma unroll
        for (int cc = 0; cc < 4; ++cc)
            #pragma unroll
            for (int k = 0; k < 9; ++k) {
                f2 w = *(const f2*)(wp + ((ci4 * 4 + cc) * 9 + k) * COUT + co0);
                acc += w * a[k / 3][k % 3][cc];
            }
    }
    f2 v; v.x = fmaxf(acc.x, 0.f); v.y = fmaxf(acc.y, 0.f);
    *(f2*)(sOut + px * SO + co0) = v;
}

// ---------------------------------------------------------------------------
// Fully fused per-grid-cell pipeline, block = (gx, gy, b), 512 threads.
// 14x14x3 cone -> conv1..6 (VALID 14->12->10->8->6->4->2) -> 2x2 pool ->
// c16[b][gy*16+gx][d][p]. Cone coords in [1,254]: padding never triggers.
// (512,2): 2 blocks/CU = 16 waves/CU; VGPR cap 128 with ~104 natural demand
// (one-strip-live discipline) -> no spill.
__global__ __launch_bounds__(512, 2)
void fused_cone(const float* __restrict__ x, const float* __restrict__ wp,
                const float* __restrict__ b1, const float* __restrict__ b2,
                const float* __restrict__ b3, const float* __restrict__ b4,
                const float* __restrict__ b5, const float* __restrict__ b6,
                float* __restrict__ c16) {
    __shared__ float sA[3600];   // xin 784 / t2 3600 / t4 2448 / L6 part 1536
    __shared__ float sB[2880];   // t1 2880 / t3 2304 / t5 1088

    const int gx = blockIdx.x, gy = blockIdx.y, b = blockIdx.z;
    const float* xb = x + (size_t)b * 3 * HW1K;

    // xin: xlow cone [14*14][stride 4]; xlow[y][x] = avg of x rows 4y+1..4y+2,
    // cols 4x+1..4x+2 (exact bilinear 4x downsample).
    for (int i = threadIdx.x; i < 588; i += 512) {
        int c  = i % 3;
        int t  = i / 3;
        int xi = t % 14;
        int yi = t / 14;
        int ya = 16 * gy + 1 + yi;
        int xa = 16 * gx + 1 + xi;
        const float* p = xb + (size_t)c * HW1K + (4 * ya + 1) * 1024 + (4 * xa + 1);
        sA[t * 4 + c] = 0.25f * (p[0] + p[1] + p[1024] + p[1025]);
    }
    __syncthreads();

    // L1: CIN=3 (scalar act reads), cog=tid%4 (16 cout / NCO4), 128 px slots,
    // 2 sequential strips cover 144 px. out t1 [144][20].
    {
        const int cog = threadIdx.x % 4, co0 = cog * 4, ps = threadIdx.x / 4;
        const f4 bs = *(const f4*)(b1 + co0);
        #pragma unroll 1
        for (int s = 0; s < 2; ++s) {
            int px = ps + s * 128; if (px > 143) px = 143;
            const int base = ((px / 12) * 14 + (px % 12)) * 4;
            f4 acc = bs;
            for (int ci = 0; ci < 3; ++ci) {
                #pragma unroll
                for (int k = 0; k < 9; ++k) {
                    f4 w = *(const f4*)(wp + (ci * 9 + k) * 16 + co0);
                    acc += w * sA[base + ((k / 3) * 14 + (k % 3)) * 4 + ci];
                }
            }
            *(f4*)(sB + px * 20 + co0) = relu4(acc);
        }
    }
    __syncthreads();

    layer_s4<12, 16, 32, 1>(sB, sA, wp + 432,   b2); __syncthreads();  // t2 [100][36]
    layer_p4<10, 32, 32>   (sA, sB, wp + 5040,  b3); __syncthreads();  // t3 [64][36]
    layer_s2co<8, 32, 64, 2>(sB, sA, wp + 14256, b4); __syncthreads(); // t4 [36][68]
    layer_p2co<6, 64, 64>  (sA, sB, wp + 32688, b5); __syncthreads();  // t5 [16][68]

    // L6: CIN=64, COUT=96, WIN=4->WOUT=2 (4 px), ci-split x4 (quarters).
    // Active: 4*96 threads; raw partials -> sA [quarter][4px][96]; no relu.
    {
        const int q = threadIdx.x >> 7;
        const int r = threadIdx.x & 127;
        if (r < 96) {
            const int cog = r % 24, co0 = cog * 4, px = r / 24;
            const int base = ((px >> 1) * 4 + (px & 1)) * 68;
            f4 acc = {0.f, 0.f, 0.f, 0.f};
            for (int ci4 = q * 4; ci4 < q * 4 + 4; ++ci4) {
                f4 a[3][3];
                #pragma unroll
                for (int rr = 0; rr < 3; ++rr)
                    #pragma unroll
                    for (int c = 0; c < 3; ++c)
                        a[rr][c] = *(const f4*)(sB + base + (rr * 4 + c) * 68 + ci4 * 4);
                #pragma unroll
                for (int cc = 0; cc < 4; ++cc)
                    #pragma unroll
                    for (int k = 0; k < 9; ++k) {
                        f4 w = *(const f4*)(wp + 69552 + ((ci4 * 4 + cc) * 9 + k) * 96 + co0);
                        acc += w * a[k / 3][k % 3][cc];
                    }
            }
            *(f4*)(sA + q * 384 + px * 96 + co0) = acc;
        }
    }
    __syncthreads();

    // pool 2x2 (exact 16x bilinear downsample) + combine quarters + bias.
    if (threadIdx.x < 96) {
        const int ch = threadIdx.x;
        float v = 0.0f;
        #pragma unroll
        for (int q = 0; q < 4; ++q)
            #pragma unroll
            for (int px = 0; px < 4; ++px)
                v += sA[q * 384 + px * 96 + ch];
        v = 0.25f * v + b6[ch];
        int p = ch >> 3, d = ch & 7;
        c16[(size_t)b * 24576 + ((gy * 16 + gx) * 8 + d) * 12 + p] = v;
    }
}

// ---------------------------------------------------------------------------
// Fused guide + trilinear slice + affine + clip; 4 px per thread (float4).
// c16 layout: [b][gy*16+gx][d][p=12].
__global__ __launch_bounds__(256)
void slice_apply4(const float* __restrict__ x, const float* __restrict__ c16,
                  float* __restrict__ out) {
    int t = blockIdx.x * 256 + threadIdx.x;      // 0 .. 2*HW1K/4 - 1
    int po4 = t * 4;
    int b   = po4 >> 20;
    int po  = po4 & (HW1K - 1);
    int py  = po >> 10;
    int px0 = po & 1023;

    const float* xb = x + (size_t)b * 3 * HW1K;
    f4 rv  = *(const f4*)(xb + po);
    f4 gv  = *(const f4*)(xb + HW1K + po);
    f4 bv  = *(const f4*)(xb + 2 * HW1K + po);

    float ysf = (float)py * (15.0f / 1023.0f);
    int y0 = (int)floorf(ysf); int y1 = min(y0 + 1, 15);
    float wy = ysf - (float)y0;

    const float* gb = c16 + (size_t)b * 24576;
    f4 outv[3];

    #pragma unroll
    for (int s = 0; s < 4; ++s) {
        float r  = rv[s], g = gv[s], bl = bv[s];
        int   px = px0 + s;

        float gd = fminf(fmaxf(0.299f * r + 0.587f * g + 0.114f * bl, 0.0f), 1.0f);

        float xsf = (float)px * (15.0f / 1023.0f);
        int x0 = (int)floorf(xsf); int x1 = min(x0 + 1, 15);
        float wx = xsf - (float)x0;

        float d  = gd * 7.0f;
        int d0 = (int)floorf(d); d0 = max(0, min(d0, 7));
        int d1 = min(d0 + 1, 7);
        float wd = fminf(fmaxf(d - (float)d0, 0.0f), 1.0f);

        float co[12];
        #pragma unroll
        for (int p = 0; p < 12; ++p) co[p] = 0.0f;

        #pragma unroll
        for (int cy = 0; cy < 2; ++cy) {
            int   yy  = cy ? y1 : y0;
            float wyf = cy ? wy : 1.0f - wy;
            #pragma unroll
            for (int cx = 0; cx < 2; ++cx) {
                int   xx  = cx ? x1 : x0;
                float wyx = wyf * (cx ? wx : 1.0f - wx);
                const float* g0 = gb + ((yy * 16 + xx) * 8 + d0) * 12;
                const float* g1 = gb + ((yy * 16 + xx) * 8 + d1) * 12;
                float wA = wyx * (1.0f - wd), wB = wyx * wd;
                #pragma unroll
                for (int p = 0; p < 12; ++p) co[p] += wA * g0[p] + wB * g1[p];
            }
        }

        #pragma unroll
        for (int i = 0; i < 3; ++i) {
            float v = co[i * 4 + 0] * r + co[i * 4 + 1] * g + co[i * 4 + 2] * bl + co[i * 4 + 3];
            outv[i][s] = fminf(fmaxf(v, 0.0f), 1.0f);
        }
    }

    float* ob = out + (size_t)b * 3 * HW1K;
    #pragma unroll
    for (int i = 0; i < 3; ++i)
        *(f4*)(ob + i * HW1K + po) = outv[i];
}

// ---------------------------------------------------------------------------
extern "C" void kernel_launch(void* const* d_in, const int* in_sizes, int n_in,
                              void* d_out, int out_size, void* d_ws, size_t ws_size,
                              hipStream_t stream) {
    const float* x  = (const float*)d_in[0];
    const float* w1 = (const float*)d_in[1];  const float* b1 = (const float*)d_in[2];
    const float* w2 = (const float*)d_in[3];  const float* b2 = (const float*)d_in[4];
    const float* w3 = (const float*)d_in[5];  const float* b3 = (const float*)d_in[6];
    const float* w4 = (const float*)d_in[7];  const float* b4 = (const float*)d_in[8];
    const float* w5 = (const float*)d_in[9];  const float* b5 = (const float*)d_in[10];
    const float* w6 = (const float*)d_in[11]; const float* b6 = (const float*)d_in[12];
    float* out = (float*)d_out;

    float* wp  = (float*)d_ws;      // 124848 floats
    float* c16 = wp + 124848;       // 2*24576 floats

    prep_w<<<dim3((124848 + 255) / 256), dim3(256), 0, stream>>>(w1, w2, w3, w4, w5, w6, wp);
    fused_cone<<<dim3(16, 16, 2), dim3(512), 0, stream>>>(x, wp, b1, b2, b3, b4, b5, b6, c16);
    slice_apply4<<<dim3(2 * HW1K / 4 / 256), dim3(256), 0, stream>>>(x, c16, out);

    (void)in_sizes; (void)n_in; (void)out_size; (void)ws_size;
}

// Round 10
// 157.492 us; speedup vs baseline: 3.2696x; 3.2696x over previous
//
#include <hip/hip_runtime.h>
#include <hip/hip_bf16.h>

#define HW1K  1048576    // 1024*1024

typedef float f4 __attribute__((ext_vector_type(4)));

__device__ __forceinline__ f4 relu4(f4 v) {
    v.x = fmaxf(v.x, 0.0f); v.y = fmaxf(v.y, 0.0f);
    v.z = fmaxf(v.z, 0.0f); v.w = fmaxf(v.w, 0.0f);
    return v;
}

// Weight-prep: OIHW -> wp[layer_base + (ci*9+ky*3+kx)*COUT + co] (co fastest:
// coalesced, f4-aligned over co; all layer bases mult of 4).
// Bases: L1@0(432) L2@432(4608) L3@5040(9216) L4@14256(18432) L5@32688(36864)
// L6@69552(55296), total 124848.
__global__ void prep_w(const float* __restrict__ w1, const float* __restrict__ w2,
                       const float* __restrict__ w3, const float* __restrict__ w4,
                       const float* __restrict__ w5, const float* __restrict__ w6,
                       float* __restrict__ wp) {
    int i = blockIdx.x * 256 + threadIdx.x;
    if (i >= 124848) return;
    const float* src; int base, cin, cout;
    if      (i < 432)   { src = w1; base = 0;     cin = 3;  cout = 16; }
    else if (i < 5040)  { src = w2; base = 432;   cin = 16; cout = 32; }
    else if (i < 14256) { src = w3; base = 5040;  cin = 32; cout = 32; }
    else if (i < 32688) { src = w4; base = 14256; cin = 32; cout = 64; }
    else if (i < 69552) { src = w5; base = 32688; cin = 64; cout = 64; }
    else                { src = w6; base = 69552; cin = 64; cout = 96; }
    int r  = i - base;
    int kk = r / cout;
    int co = r % cout;
    int ci = kk / 9;
    int t9 = kk % 9;
    wp[i] = src[(co * cin + ci) * 9 + t9];
}

// Load 9 f4 weights for input channel CI into register array W.
#define LOADW(W, CI)                                               \
    _Pragma("unroll")                                              \
    for (int k = 0; k < 9; ++k)                                    \
        W[k] = *(const f4*)(wb + ((CI) * 9 + k) * COUT);

// 2-px strip FMA group for one input channel (component CC of act f4).
#define STRIP_FMA(W, CC)                                           \
    {                                                              \
        _Pragma("unroll")                                          \
        for (int ky = 0; ky < 3; ++ky) {                           \
            _Pragma("unroll")                                      \
            for (int kx = 0; kx < 3; ++kx) {                       \
                acc0 += W[ky * 3 + kx] * a[ky][kx][CC];            \
                acc1 += W[ky * 3 + kx] * a[ky][kx + 1][CC];        \
            }                                                      \
        }                                                          \
    }

// 1-px FMA group.
#define PX_FMA(W, CC)                                              \
    {                                                              \
        _Pragma("unroll")                                          \
        for (int ky = 0; ky < 3; ++ky) {                           \
            _Pragma("unroll")                                      \
            for (int kx = 0; kx < 3; ++kx)                         \
                acc += W[ky * 3 + kx] * a[ky][kx][CC];             \
        }                                                          \
    }

// ---------------------------------------------------------------------------
// Strip conv layer on LDS (256 threads), NCO=4, software-pipelined weights:
// ping-pong wA/wB so FMAs for ci overlap the global loads for ci+1 (last
// group prefetches the next ci4-block's first channel). Acts: 12 ds_read_b128
// per ci4 feed 288 FMAs. Strides SI=CIN+4, SO=COUT+4.
template <int WIN, int CIN, int COUT, int SPT, int RELU>
__device__ __forceinline__ void layer_s(const float* __restrict__ sIn, float* __restrict__ sOut,
                                        const float* __restrict__ wp, const float* __restrict__ bias) {
    constexpr int WOUT  = WIN - 2;
    constexpr int SI    = CIN + 4;
    constexpr int SO    = COUT + 4;
    constexpr int COG   = COUT / 4;
    constexpr int SLOTS = 256 / COG;
    constexpr int HSTR  = WOUT / 2;
    constexpr int NSTR  = WOUT * HSTR;

    const int t   = threadIdx.x;
    const int cog = t % COG;
    const int co0 = cog * 4;
    const int ps  = t / COG;
    const f4 bs   = *(const f4*)(bias + co0);
    const float* wb = wp + co0;

    #pragma unroll 1
    for (int s = 0; s < SPT; ++s) {
        int ss = ps + s * SLOTS;
        if (ss > NSTR - 1) ss = NSTR - 1;          // duplicate slots: same value
        const int row  = ss / HSTR;
        const int col2 = (ss % HSTR) * 2;
        const int base = (row * WIN + col2) * SI;

        f4 acc0 = bs, acc1 = bs;
        f4 wA[9], wB[9];
        LOADW(wA, 0);

        #pragma unroll 1
        for (int ci4 = 0; ci4 < CIN / 4; ++ci4) {
            f4 a[3][4];
            #pragma unroll
            for (int r = 0; r < 3; ++r)
                #pragma unroll
                for (int c = 0; c < 4; ++c)
                    a[r][c] = *(const f4*)(sIn + base + (r * WIN + c) * SI + ci4 * 4);
            const int cb = ci4 * 4;
            LOADW(wB, cb + 1); STRIP_FMA(wA, 0);
            LOADW(wA, cb + 2); STRIP_FMA(wB, 1);
            LOADW(wB, cb + 3); STRIP_FMA(wA, 2);
            LOADW(wA, cb + 4); STRIP_FMA(wB, 3);   // preloads next ci4's cc=0
        }
        const int opx = row * WOUT + col2;
        *(f4*)(sOut + opx * SO + co0)       = RELU ? relu4(acc0) : acc0;
        *(f4*)(sOut + (opx + 1) * SO + co0) = RELU ? relu4(acc1) : acc1;
    }
}

// 1-px-per-thread variant (L5: 16 px x 16 cog = 256 exact), same pipeline.
template <int WIN, int CIN, int COUT, int RELU>
__device__ __forceinline__ void layer_p(const float* __restrict__ sIn, float* __restrict__ sOut,
                                        const float* __restrict__ wp, const float* __restrict__ bias) {
    constexpr int WOUT = WIN - 2;
    constexpr int SI   = CIN + 4;
    constexpr int SO   = COUT + 4;
    constexpr int COG  = COUT / 4;

    const int t   = threadIdx.x;
    const int cog = t % COG;
    const int co0 = cog * 4;
    const int px  = t / COG;
    const int row = px / WOUT, col = px % WOUT;
    const int base = (row * WIN + col) * SI;
    const float* wb = wp + co0;

    f4 acc = *(const f4*)(bias + co0);
    f4 wA[9], wB[9];
    LOADW(wA, 0);

    #pragma unroll 1
    for (int ci4 = 0; ci4 < CIN / 4; ++ci4) {
        f4 a[3][3];
        #pragma unroll
        for (int r = 0; r < 3; ++r)
            #pragma unroll
            for (int c = 0; c < 3; ++c)
                a[r][c] = *(const f4*)(sIn + base + (r * WIN + c) * SI + ci4 * 4);
        const int cb = ci4 * 4;
        LOADW(wB, cb + 1); PX_FMA(wA, 0);
        LOADW(wA, cb + 2); PX_FMA(wB, 1);
        LOADW(wB, cb + 3); PX_FMA(wA, 2);
        LOADW(wA, cb + 4); PX_FMA(wB, 3);
    }
    *(f4*)(sOut + px * SO + co0) = RELU ? relu4(acc) : acc;
}

// ---------------------------------------------------------------------------
// Fully fused per-grid-cell pipeline, block = (gx, gy, b), 256 threads.
// 14x14x3 cone -> conv1..6 (VALID 14->12->10->8->6->4->2) -> 2x2 pool ->
// c16[b][gy*16+gx][d][p]. Cone coords in [1,254]: padding never triggers.
// (256,2): 2 waves/SIMD min -> 256-VGPR cap; grid-capped at 2 blocks/CU, so
// the spare register file funds the weight software-pipeline.
__global__ __launch_bounds__(256, 2)
void fused_cone(const float* __restrict__ x, const float* __restrict__ wp,
                const float* __restrict__ b1, const float* __restrict__ b2,
                const float* __restrict__ b3, const float* __restrict__ b4,
                const float* __restrict__ b5, const float* __restrict__ b6,
                float* __restrict__ c16) {
    __shared__ float sA[3600];   // xin 784 / t2 3600 / t4 2448 / L6 part 768
    __shared__ float sB[2880];   // t1 2880 / t3 2304 / t5 1088

    const int gx = blockIdx.x, gy = blockIdx.y, b = blockIdx.z;
    const float* xb = x + (size_t)b * 3 * HW1K;

    // xin: xlow cone [14*14][stride 4]; xlow[y][x] = avg of x rows 4y+1..4y+2,
    // cols 4x+1..4x+2 (exact bilinear 4x downsample).
    for (int i = threadIdx.x; i < 588; i += 256) {
        int c  = i % 3;
        int t  = i / 3;
        int xi = t % 14;
        int yi = t / 14;
        int ya = 16 * gy + 1 + yi;
        int xa = 16 * gx + 1 + xi;
        const float* p = xb + (size_t)c * HW1K + (4 * ya + 1) * 1024 + (4 * xa + 1);
        sA[t * 4 + c] = 0.25f * (p[0] + p[1] + p[1024] + p[1025]);
    }
    __syncthreads();

    // L1: CIN=3 (scalar act reads), cog=tid%4, 64 px-slots, 3 strips cover
    // 144 px. out t1 [144][20].
    {
        const int cog = threadIdx.x % 4, co0 = cog * 4, ps = threadIdx.x / 4;
        const f4 bs = *(const f4*)(b1 + co0);
        #pragma unroll 1
        for (int s = 0; s < 3; ++s) {
            int px = ps + s * 64; if (px > 143) px = 143;
            const int base = ((px / 12) * 14 + (px % 12)) * 4;
            f4 acc = bs;
            for (int ci = 0; ci < 3; ++ci) {
                #pragma unroll
                for (int k = 0; k < 9; ++k) {
                    f4 w = *(const f4*)(wp + (ci * 9 + k) * 16 + co0);
                    acc += w * sA[base + ((k / 3) * 14 + (k % 3)) * 4 + ci];
                }
            }
            *(f4*)(sB + px * 20 + co0) = relu4(acc);
        }
    }
    __syncthreads();

    layer_s<12, 16, 32, 2, 1>(sB, sA, wp + 432,   b2); __syncthreads();  // t2 [100][36]
    layer_s<10, 32, 32, 1, 1>(sA, sB, wp + 5040,  b3); __syncthreads();  // t3 [64][36]
    layer_s< 8, 32, 64, 2, 1>(sB, sA, wp + 14256, b4); __syncthreads(); // t4 [36][68]
    layer_p< 6, 64, 64, 1>   (sA, sB, wp + 32688, b5); __syncthreads();  // t5 [16][68]

    // L6: CIN=64, COUT=96, WIN=4->WOUT=2 (4 px), ci-split x2 halves; raw
    // partials -> sA [half][4px][96]; bias added at pool. Same w-pipeline.
    {
        const int half = threadIdx.x >> 7;
        const int r    = threadIdx.x & 127;
        if (r < 96) {
            const int cog = r % 24, co0 = cog * 4, px = r / 24;
            const int base = ((px >> 1) * 4 + (px & 1)) * 68;
            const float* wb = wp + 69552 + co0;
            constexpr int COUT = 96;
            f4 acc = {0.f, 0.f, 0.f, 0.f};
            f4 wA[9], wB[9];
            const int ci0 = half * 32;
            LOADW(wA, ci0);
            #pragma unroll 1
            for (int ci4 = half * 8; ci4 < half * 8 + 8; ++ci4) {
                f4 a[3][3];
                #pragma unroll
                for (int rr = 0; rr < 3; ++rr)
                    #pragma unroll
                    for (int c = 0; c < 3; ++c)
                        a[rr][c] = *(const f4*)(sB + base + (rr * 4 + c) * 68 + ci4 * 4);
                const int cb = ci4 * 4;
                LOADW(wB, cb + 1); PX_FMA(wA, 0);
                LOADW(wA, cb + 2); PX_FMA(wB, 1);
                LOADW(wB, cb + 3); PX_FMA(wA, 2);
                LOADW(wA, cb + 4); PX_FMA(wB, 3);
            }
            *(f4*)(sA + half * 384 + px * 96 + co0) = acc;
        }
    }
    __syncthreads();

    // pool 2x2 (exact 16x bilinear downsample) + combine halves + bias.
    if (threadIdx.x < 96) {
        const int ch = threadIdx.x;
        float v = 0.0f;
        #pragma unroll
        for (int px = 0; px < 4; ++px)
            v += sA[px * 96 + ch] + sA[384 + px * 96 + ch];
        v = 0.25f * v + b6[ch];
        int p = ch >> 3, d = ch & 7;
        c16[(size_t)b * 24576 + ((gy * 16 + gx) * 8 + d) * 12 + p] = v;
    }
}

// ---------------------------------------------------------------------------
// Fused guide + trilinear slice + affine + clip; 4 px per thread (float4).
// c16 layout: [b][gy*16+gx][d][p=12].
__global__ __launch_bounds__(256)
void slice_apply4(const float* __restrict__ x, const float* __restrict__ c16,
                  float* __restrict__ out) {
    int t = blockIdx.x * 256 + threadIdx.x;      // 0 .. 2*HW1K/4 - 1
    int po4 = t * 4;
    int b   = po4 >> 20;
    int po  = po4 & (HW1K - 1);
    int py  = po >> 10;
    int px0 = po & 1023;

    const float* xb = x + (size_t)b * 3 * HW1K;
    f4 rv  = *(const f4*)(xb + po);
    f4 gv  = *(const f4*)(xb + HW1K + po);
    f4 bv  = *(const f4*)(xb + 2 * HW1K + po);

    float ysf = (float)py * (15.0f / 1023.0f);
    int y0 = (int)floorf(ysf); int y1 = min(y0 + 1, 15);
    float wy = ysf - (float)y0;

    const float* gb = c16 + (size_t)b * 24576;
    f4 outv[3];

    #pragma unroll
    for (int s = 0; s < 4; ++s) {
        float r  = rv[s], g = gv[s], bl = bv[s];
        int   px = px0 + s;

        float gd = fminf(fmaxf(0.299f * r + 0.587f * g + 0.114f * bl, 0.0f), 1.0f);

        float xsf = (float)px * (15.0f / 1023.0f);
        int x0 = (int)floorf(xsf); int x1 = min(x0 + 1, 15);
        float wx = xsf - (float)x0;

        float d  = gd * 7.0f;
        int d0 = (int)floorf(d); d0 = max(0, min(d0, 7));
        int d1 = min(d0 + 1, 7);
        float wd = fminf(fmaxf(d - (float)d0, 0.0f), 1.0f);

        float co[12];
        #pragma unroll
        for (int p = 0; p < 12; ++p) co[p] = 0.0f;

        #pragma unroll
        for (int cy = 0; cy < 2; ++cy) {
            int   yy  = cy ? y1 : y0;
            float wyf = cy ? wy : 1.0f - wy;
            #pragma unroll
            for (int cx = 0; cx < 2; ++cx) {
                int   xx  = cx ? x1 : x0;
                float wyx = wyf * (cx ? wx : 1.0f - wx);
                const float* g0 = gb + ((yy * 16 + xx) * 8 + d0) * 12;
                const float* g1 = gb + ((yy * 16 + xx) * 8 + d1) * 12;
                float wA = wyx * (1.0f - wd), wB = wyx * wd;
                #pragma unroll
                for (int p = 0; p < 12; ++p) co[p] += wA * g0[p] + wB * g1[p];
            }
        }

        #pragma unroll
        for (int i = 0; i < 3; ++i) {
            float v = co[i * 4 + 0] * r + co[i * 4 + 1] * g + co[i * 4 + 2] * bl + co[i * 4 + 3];
            outv[i][s] = fminf(fmaxf(v, 0.0f), 1.0f);
        }
    }

    float* ob = out + (size_t)b * 3 * HW1K;
    #pragma unroll
    for (int i = 0; i < 3; ++i)
        *(f4*)(ob + i * HW1K + po) = outv[i];
}

// ---------------------------------------------------------------------------
extern "C" void kernel_launch(void* const* d_in, const int* in_sizes, int n_in,
                              void* d_out, int out_size, void* d_ws, size_t ws_size,
                              hipStream_t stream) {
    const float* x  = (const float*)d_in[0];
    const float* w1 = (const float*)d_in[1];  const float* b1 = (const float*)d_in[2];
    const float* w2 = (const float*)d_in[3];  const float* b2 = (const float*)d_in[4];
    const float* w3 = (const float*)d_in[5];  const float* b3 = (const float*)d_in[6];
    const float* w4 = (const float*)d_in[7];  const float* b4 = (const float*)d_in[8];
    const float* w5 = (const float*)d_in[9];  const float* b5 = (const float*)d_in[10];
    const float* w6 = (const float*)d_in[11]; const float* b6 = (const float*)d_in[12];
    float* out = (float*)d_out;

    float* wp  = (float*)d_ws;          // 124848 floats
    float* c16 = wp + 124848 + 1024;    // +1KB pad: w-pipeline overreads <=864 floats past wp

    prep_w<<<dim3((124848 + 255) / 256), dim3(256), 0, stream>>>(w1, w2, w3, w4, w5, w6, wp);
    fused_cone<<<dim3(16, 16, 2), dim3(256), 0, stream>>>(x, wp, b1, b2, b3, b4, b5, b6, c16);
    slice_apply4<<<dim3(2 * HW1K / 4 / 256), dim3(256), 0, stream>>>(x, c16, out);

    (void)in_sizes; (void)n_in; (void)out_size; (void)ws_size;
}